// Round 2
// baseline (111.378 us; speedup 1.0000x reference)
//
#include <hip/hip_runtime.h>
#include <hip/hip_bf16.h>
#include <cstdint>

// Problem constants (ConceptBoxModel): B=256, L=512, N=64, D=32, C=100
constexpr int Bb = 256, Ll = 512, Nn = 64, Dd = 32, Cc = 100;
constexpr float EPS = 1e-6f;

// ---------------------------------------------------------------------------
// Kernel A: x_m = h@Wc + bc ; delta = softplus(h@Wo + bo) ; p_hat
// grid (n=64, btile=4), block 256.  Each block: one n, 64 b-rows, 32 d-cols.
// ---------------------------------------------------------------------------
__global__ __launch_bounds__(256) void kA(
    const float* __restrict__ h,    // [256][512]
    const float* __restrict__ Wc,   // [64][512][32]
    const float* __restrict__ bc,   // [64][32]
    const float* __restrict__ Wo,
    const float* __restrict__ bo,
    const float* __restrict__ Wp,   // [64][64]
    const float* __restrict__ bp,   // [64]
    float* __restrict__ xm_ws,      // [256][64][32] f32
    float* __restrict__ dl_ws,      // [256][64][32] f32
    float* __restrict__ ph_ws,      // [256][64]     f32
    float* __restrict__ out_ph)     // [256][64]
{
  const int n  = blockIdx.x;
  const int bt = blockIdx.y * 64;
  const int t  = threadIdx.x;
  __shared__ float hs[64][32];   // broadcast reads only -> no pad needed
  __shared__ float wcs[32][32];  // [kk][d], lanes read consecutive d
  __shared__ float wos[32][32];

  const int d = t & 31, r0 = t >> 5;
  float accc[8] = {0,0,0,0,0,0,0,0};
  float acco[8] = {0,0,0,0,0,0,0,0};

  for (int k0 = 0; k0 < Ll; k0 += 32) {
    __syncthreads();
    // h tile: rows bt..bt+63, cols k0..k0+31  (8 floats per thread)
    {
      const int r = t >> 2, kk = (t & 3) * 8;
      const float* hp = h + (bt + r) * Ll + k0 + kk;
      float4 h0 = *(const float4*)(hp);
      float4 h1 = *(const float4*)(hp + 4);
      *(float4*)&hs[r][kk]     = h0;
      *(float4*)&hs[r][kk + 4] = h1;
    }
    // W tiles: 32x32 contiguous at n*16384 + k0*32  (4 floats per thread)
    {
      float4 wv = *(const float4*)(Wc + n * (Ll * Dd) + k0 * Dd + t * 4);
      float4 ov = *(const float4*)(Wo + n * (Ll * Dd) + k0 * Dd + t * 4);
      *(float4*)(&wcs[0][0] + t * 4) = wv;
      *(float4*)(&wos[0][0] + t * 4) = ov;
    }
    __syncthreads();
    #pragma unroll 8
    for (int kk = 0; kk < 32; kk++) {
      const float wc = wcs[kk][d], wo = wos[kk][d];
      #pragma unroll
      for (int j = 0; j < 8; j++) {
        const float hv = hs[r0 * 8 + j][kk];   // uniform per half-wave
        accc[j] += hv * wc;
        acco[j] += hv * wo;
      }
    }
  }

  const float bcv  = bc[n * Dd + d];
  const float bov  = bo[n * Dd + d];
  const float wplo = Wp[n * 64 + d];
  const float wphi = Wp[n * 64 + 32 + d];
  const float bpv  = bp[n];

  #pragma unroll
  for (int j = 0; j < 8; j++) {
    const int b = bt + r0 * 8 + j;
    const float xm  = accc[j] + bcv;
    const float pre = acco[j] + bov;
    // stable softplus = max(x,0) + log1p(exp(-|x|))
    const float dl = fmaxf(pre, 0.f) + log1pf(expf(-fabsf(pre)));
    xm_ws[b * 2048 + n * Dd + d] = xm;
    dl_ws[b * 2048 + n * Dd + d] = dl;
    float pp = xm * wplo + dl * wphi;
    pp += __shfl_xor(pp, 1);
    pp += __shfl_xor(pp, 2);
    pp += __shfl_xor(pp, 4);
    pp += __shfl_xor(pp, 8);
    pp += __shfl_xor(pp, 16);
    if (d == 0) {
      const float ph = 1.f / (1.f + expf(-(pp + bpv)));
      ph_ws[b * 64 + n] = ph;
      out_ph[b * 64 + n] = ph;
    }
  }
}

// ---------------------------------------------------------------------------
// Kernel B: pairwise intersection volumes V[b,i,j].  One block per b.
// ---------------------------------------------------------------------------
__global__ __launch_bounds__(256) void kB(
    const float* __restrict__ xm_ws,
    const float* __restrict__ dl_ws,
    float* __restrict__ out_V)      // [256][64][64]
{
  const int b = blockIdx.x, t = threadIdx.x;
  __shared__ float lo[64][36];   // pad 36: float4-aligned, banks spread
  __shared__ float hi[64][36];
  __shared__ float rvol[64];

  {
    const int n = t >> 2, dd = (t & 3) * 8;
    const float* xp = xm_ws + b * 2048 + n * Dd + dd;
    const float* dp = dl_ws + b * 2048 + n * Dd + dd;
    #pragma unroll
    for (int i = 0; i < 8; i += 4) {
      float4 x = *(const float4*)(xp + i);
      float4 g = *(const float4*)(dp + i);
      lo[n][dd + i + 0] = x.x - g.x;  hi[n][dd + i + 0] = x.x + g.x;
      lo[n][dd + i + 1] = x.y - g.y;  hi[n][dd + i + 1] = x.y + g.y;
      lo[n][dd + i + 2] = x.z - g.z;  hi[n][dd + i + 2] = x.z + g.z;
      lo[n][dd + i + 3] = x.w - g.w;  hi[n][dd + i + 3] = x.w + g.w;
    }
  }
  if (t < 64) {
    const float* dp = dl_ws + b * 2048 + t * Dd;
    float p = 1.f;
    #pragma unroll
    for (int dd = 0; dd < 32; dd++) p *= dp[dd] + EPS;
    rvol[t] = 1.f / p;
  }
  __syncthreads();

  const int i0 = t >> 6;    // wave id -> i uniform per wave
  const int j  = t & 63;
  #pragma unroll 1
  for (int it = 0; it < 16; it++) {
    const int i = i0 + 4 * it;
    float prod = 1.f;
    #pragma unroll
    for (int dd = 0; dd < 32; dd += 4) {
      float4 hj = *(const float4*)&hi[j][dd];
      float4 lj = *(const float4*)&lo[j][dd];
      float4 hv = *(const float4*)&hi[i][dd];   // broadcast
      float4 lv = *(const float4*)&lo[i][dd];   // broadcast
      float v0 = fmaxf(fminf(hv.x, hj.x) - fmaxf(lv.x, lj.x), 0.f) * 0.5f + EPS;
      float v1 = fmaxf(fminf(hv.y, hj.y) - fmaxf(lv.y, lj.y), 0.f) * 0.5f + EPS;
      float v2 = fmaxf(fminf(hv.z, hj.z) - fmaxf(lv.z, lj.z), 0.f) * 0.5f + EPS;
      float v3 = fmaxf(fminf(hv.w, hj.w) - fmaxf(lv.w, lj.w), 0.f) * 0.5f + EPS;
      prod *= v0 * v1 * v2 * v3;
    }
    out_V[b * 4096 + i * 64 + j] = prod * rvol[j];
  }
}

// ---------------------------------------------------------------------------
// Kernel C: y = aligned@W1 + b1 + V@W2 + b2.  One block per b.
// ty=0 computes aligned@W1, ty=1 computes V@W2, LDS reduce.
// ---------------------------------------------------------------------------
__global__ __launch_bounds__(256) void kC(
    const float* __restrict__ xm_ws,
    const float* __restrict__ dl_ws,
    const float* __restrict__ ph_ws,
    const float* __restrict__ Vb,   // V f32, read back from d_out
    const float* __restrict__ W1,   // [4096][100]
    const float* __restrict__ b1,
    const float* __restrict__ W2,   // [4096][100]
    const float* __restrict__ b2,
    float* __restrict__ out_y)      // [256][100]
{
  const int b = blockIdx.x, t = threadIdx.x;
  __shared__ float arow[4096];
  __shared__ float vrow[4096];
  __shared__ float part[2][128];

  for (int m = t; m < 4096; m += 256) {
    const int n = m >> 6, kk = m & 63;
    const float v = (kk < 32) ? xm_ws[b * 2048 + n * Dd + kk]
                              : dl_ws[b * 2048 + n * Dd + (kk - 32)];
    arow[m] = v * ph_ws[b * 64 + n];
    vrow[m] = Vb[b * 4096 + m];
  }
  __syncthreads();

  const int tx = t & 127, ty = t >> 7;
  const float* A = ty ? vrow : arow;
  const float* W = ty ? W2 : W1;
  float acc0 = 0.f, acc1 = 0.f, acc2 = 0.f, acc3 = 0.f;
  if (tx < Cc) {
    const float* wp = W + tx;
    for (int m = 0; m < 4096; m += 4) {
      float4 a = *(const float4*)&A[m];
      acc0 += a.x * wp[(m + 0) * Cc];
      acc1 += a.y * wp[(m + 1) * Cc];
      acc2 += a.z * wp[(m + 2) * Cc];
      acc3 += a.w * wp[(m + 3) * Cc];
    }
  }
  part[ty][tx] = (acc0 + acc1) + (acc2 + acc3);
  __syncthreads();
  if (ty == 0 && tx < Cc) {
    const float y = part[0][tx] + part[1][tx] + b1[tx] + b2[tx];
    out_y[b * Cc + tx] = y;
  }
}

// ---------------------------------------------------------------------------
extern "C" void kernel_launch(void* const* d_in, const int* in_sizes, int n_in,
                              void* d_out, int out_size, void* d_ws, size_t ws_size,
                              hipStream_t stream) {
  const float* h  = (const float*)d_in[0];
  const float* Wc = (const float*)d_in[1];
  const float* bc = (const float*)d_in[2];
  const float* Wo = (const float*)d_in[3];
  const float* bo = (const float*)d_in[4];
  const float* Wp = (const float*)d_in[5];
  const float* bp = (const float*)d_in[6];
  const float* W1 = (const float*)d_in[7];
  const float* b1 = (const float*)d_in[8];
  const float* W2 = (const float*)d_in[9];
  const float* b2 = (const float*)d_in[10];

  float* out    = (float*)d_out;
  float* out_y  = out;                         // [256][100]
  float* out_ph = out + Bb * Cc;               // [256][64]
  float* out_V  = out + Bb * Cc + Bb * Nn;     // [256][64][64]

  float* xm = (float*)d_ws;            // 524288 f32
  float* dl = xm + Bb * Nn * Dd;       // 524288 f32
  float* ph = dl + Bb * Nn * Dd;       // 16384 f32   (total ~4.3 MB)

  kA<<<dim3(Nn, Bb / 64), 256, 0, stream>>>(h, Wc, bc, Wo, bo, Wp, bp,
                                            xm, dl, ph, out_ph);
  kB<<<Bb, 256, 0, stream>>>(xm, dl, out_V);
  kC<<<Bb, 256, 0, stream>>>(xm, dl, ph, (const float*)out_V,
                             W1, b1, W2, b2, out_y);
}

// Round 3
// 73.968 us; speedup vs baseline: 1.5058x; 1.5058x over previous
//
#include <hip/hip_runtime.h>
#include <hip/hip_bf16.h>
#include <cstdint>

// Problem constants (ConceptBoxModel): B=256, L=512, N=64, D=32, C=100
constexpr int Bb = 256, Ll = 512, Nn = 64, Dd = 32, Cc = 100;
constexpr float EPS = 1e-6f;

// ---------------------------------------------------------------------------
// Kernel A: x_m = h@Wc + bc ; delta = softplus(h@Wo + bo) ; p_hat
// grid (n=64, btile=4), block 256.  Each block: one n, 64 b-rows, 32 d-cols.
// ---------------------------------------------------------------------------
__global__ __launch_bounds__(256) void kA(
    const float* __restrict__ h,    // [256][512]
    const float* __restrict__ Wc,   // [64][512][32]
    const float* __restrict__ bc,   // [64][32]
    const float* __restrict__ Wo,
    const float* __restrict__ bo,
    const float* __restrict__ Wp,   // [64][64]
    const float* __restrict__ bp,   // [64]
    float* __restrict__ xm_ws,      // [256][64][32] f32
    float* __restrict__ dl_ws,      // [256][64][32] f32
    float* __restrict__ ph_ws,      // [256][64]     f32
    float* __restrict__ out_ph)     // [256][64]
{
  const int n  = blockIdx.x;
  const int bt = blockIdx.y * 64;
  const int t  = threadIdx.x;
  __shared__ float hsT[32][68];  // [kk][row], 68*4=272B row (16B-aligned)
  __shared__ float wcs[32][32];  // [kk][d], lanes read consecutive d
  __shared__ float wos[32][32];

  const int d = t & 31, r0 = t >> 5;
  float accc[8] = {0,0,0,0,0,0,0,0};
  float acco[8] = {0,0,0,0,0,0,0,0};

  for (int k0 = 0; k0 < Ll; k0 += 32) {
    __syncthreads();
    // h tile transposed: hsT[kk][row] for rows bt..bt+63, kk = k0..k0+31
    {
      const int r = t >> 2, kk8 = (t & 3) * 8;
      const float* hp = h + (bt + r) * Ll + k0 + kk8;
      float4 h0 = *(const float4*)(hp);
      float4 h1 = *(const float4*)(hp + 4);
      hsT[kk8 + 0][r] = h0.x; hsT[kk8 + 1][r] = h0.y;
      hsT[kk8 + 2][r] = h0.z; hsT[kk8 + 3][r] = h0.w;
      hsT[kk8 + 4][r] = h1.x; hsT[kk8 + 5][r] = h1.y;
      hsT[kk8 + 6][r] = h1.z; hsT[kk8 + 7][r] = h1.w;
    }
    // W tiles: 32x32 contiguous at n*16384 + k0*32  (4 floats per thread)
    {
      float4 wv = *(const float4*)(Wc + n * (Ll * Dd) + k0 * Dd + t * 4);
      float4 ov = *(const float4*)(Wo + n * (Ll * Dd) + k0 * Dd + t * 4);
      *(float4*)(&wcs[0][0] + t * 4) = wv;
      *(float4*)(&wos[0][0] + t * 4) = ov;
    }
    __syncthreads();
    #pragma unroll 8
    for (int kk = 0; kk < 32; kk++) {
      const float wc = wcs[kk][d], wo = wos[kk][d];
      float4 hA = *(const float4*)&hsT[kk][r0 * 8];
      float4 hB = *(const float4*)&hsT[kk][r0 * 8 + 4];
      accc[0] += hA.x * wc;  acco[0] += hA.x * wo;
      accc[1] += hA.y * wc;  acco[1] += hA.y * wo;
      accc[2] += hA.z * wc;  acco[2] += hA.z * wo;
      accc[3] += hA.w * wc;  acco[3] += hA.w * wo;
      accc[4] += hB.x * wc;  acco[4] += hB.x * wo;
      accc[5] += hB.y * wc;  acco[5] += hB.y * wo;
      accc[6] += hB.z * wc;  acco[6] += hB.z * wo;
      accc[7] += hB.w * wc;  acco[7] += hB.w * wo;
    }
  }

  const float bcv  = bc[n * Dd + d];
  const float bov  = bo[n * Dd + d];
  const float wplo = Wp[n * 64 + d];
  const float wphi = Wp[n * 64 + 32 + d];
  const float bpv  = bp[n];

  #pragma unroll
  for (int j = 0; j < 8; j++) {
    const int b = bt + r0 * 8 + j;
    const float xm  = accc[j] + bcv;
    const float pre = acco[j] + bov;
    // stable softplus = max(x,0) + log1p(exp(-|x|))
    const float dl = fmaxf(pre, 0.f) + log1pf(expf(-fabsf(pre)));
    xm_ws[b * 2048 + n * Dd + d] = xm;
    dl_ws[b * 2048 + n * Dd + d] = dl;
    float pp = xm * wplo + dl * wphi;
    pp += __shfl_xor(pp, 1);
    pp += __shfl_xor(pp, 2);
    pp += __shfl_xor(pp, 4);
    pp += __shfl_xor(pp, 8);
    pp += __shfl_xor(pp, 16);
    if (d == 0) {
      const float ph = 1.f / (1.f + expf(-(pp + bpv)));
      ph_ws[b * 64 + n] = ph;
      out_ph[b * 64 + n] = ph;
    }
  }
}

// ---------------------------------------------------------------------------
// Kernel B: pairwise intersection volumes V[b,i,j].  One block per b.
// ---------------------------------------------------------------------------
__global__ __launch_bounds__(256) void kB(
    const float* __restrict__ xm_ws,
    const float* __restrict__ dl_ws,
    float* __restrict__ out_V)      // [256][64][64]
{
  const int b = blockIdx.x, t = threadIdx.x;
  __shared__ float lo[64][36];   // pad 36: float4-aligned, banks spread
  __shared__ float hi[64][36];
  __shared__ float rvol[64];

  {
    const int n = t >> 2, dd = (t & 3) * 8;
    const float* xp = xm_ws + b * 2048 + n * Dd + dd;
    const float* dp = dl_ws + b * 2048 + n * Dd + dd;
    #pragma unroll
    for (int i = 0; i < 8; i += 4) {
      float4 x = *(const float4*)(xp + i);
      float4 g = *(const float4*)(dp + i);
      lo[n][dd + i + 0] = x.x - g.x;  hi[n][dd + i + 0] = x.x + g.x;
      lo[n][dd + i + 1] = x.y - g.y;  hi[n][dd + i + 1] = x.y + g.y;
      lo[n][dd + i + 2] = x.z - g.z;  hi[n][dd + i + 2] = x.z + g.z;
      lo[n][dd + i + 3] = x.w - g.w;  hi[n][dd + i + 3] = x.w + g.w;
    }
  }
  if (t < 64) {
    const float* dp = dl_ws + b * 2048 + t * Dd;
    float p = 1.f;
    #pragma unroll
    for (int dd = 0; dd < 32; dd++) p *= dp[dd] + EPS;
    rvol[t] = 1.f / p;
  }
  __syncthreads();

  const int i0 = t >> 6;    // wave id -> i uniform per wave
  const int j  = t & 63;
  #pragma unroll 1
  for (int it = 0; it < 16; it++) {
    const int i = i0 + 4 * it;
    float prod = 1.f;
    #pragma unroll
    for (int dd = 0; dd < 32; dd += 4) {
      float4 hj = *(const float4*)&hi[j][dd];
      float4 lj = *(const float4*)&lo[j][dd];
      float4 hv = *(const float4*)&hi[i][dd];   // broadcast
      float4 lv = *(const float4*)&lo[i][dd];   // broadcast
      float v0 = fmaxf(fminf(hv.x, hj.x) - fmaxf(lv.x, lj.x), 0.f) * 0.5f + EPS;
      float v1 = fmaxf(fminf(hv.y, hj.y) - fmaxf(lv.y, lj.y), 0.f) * 0.5f + EPS;
      float v2 = fmaxf(fminf(hv.z, hj.z) - fmaxf(lv.z, lj.z), 0.f) * 0.5f + EPS;
      float v3 = fmaxf(fminf(hv.w, hj.w) - fmaxf(lv.w, lj.w), 0.f) * 0.5f + EPS;
      prod *= v0 * v1 * v2 * v3;
    }
    out_V[b * 4096 + i * 64 + j] = prod * rvol[j];
  }
}

// ---------------------------------------------------------------------------
// Kernel C1: split-K GEMM partials.
//   A = concat([aligned, V]) : [256][8192], W = [W1; W2] : [8192][100]
//   grid (bg=8, s=32): block computes rows bg*32..+32, all 128 (100) cols,
//   K-slice of 256 (s<16 -> aligned@W1 slice, s>=16 -> V@W2 slice).
//   Thread tile: 2 rows x 8 cols (quads tx and tx+16).
// ---------------------------------------------------------------------------
__global__ __launch_bounds__(256) void kC1(
    const float* __restrict__ xm_ws,   // [256][2048]
    const float* __restrict__ dl_ws,   // [256][2048]
    const float* __restrict__ ph_ws,   // [256][64]
    const float* __restrict__ Vb,      // [256][4096] (from d_out)
    const float* __restrict__ W1,      // [4096][100]
    const float* __restrict__ W2,      // [4096][100]
    float* __restrict__ part)          // [32][256][100]
{
  const int bg = blockIdx.x;           // 8 row-groups of 32
  const int s  = blockIdx.y;           // 32 K-slices
  const bool isV = (s >= 16);
  const int m0 = (s & 15) * 256;       // type-local K offset, KSL=256
  const float* __restrict__ W = isV ? W2 : W1;

  __shared__ float Wt[64][132];        // [kk][col], 132*4=528B = 33*16 aligned
  __shared__ float At[64][33];         // [kk][row]

  const int t  = threadIdx.x;
  const int tx = t & 15;               // col quads tx, tx+16
  const int ty = t >> 4;               // rows ty*2, ty*2+1

  float acc[2][8] = {};

  // staging thread maps
  const int wrw = t >> 2, wq8 = (t & 3) * 8;       // W: row, granule base
  const int arow = t >> 3, agk = t & 7;            // A: row, kk-octet
  const int brow_s = bg * 32 + arow;

  for (int ch = 0; ch < 4; ch++) {
    const int mbase = m0 + ch * 64;
    __syncthreads();
    // ---- stage W chunk [64][<=100 cols] ----
    {
      const float* wr = W + (mbase + wrw) * Cc;
      #pragma unroll
      for (int j = 0; j < 8; j++) {
        const int c = (wq8 + j) * 4;
        float4 v = make_float4(0.f, 0.f, 0.f, 0.f);
        if (c < Cc) v = *(const float4*)(wr + c);
        *(float4*)&Wt[wrw][c] = v;
      }
    }
    // ---- stage A chunk [64 kk][32 rows] ----
    {
      const int mk = mbase + agk * 8;              // 8-run, stays in one n/half
      float4 v0, v1;
      if (!isV) {
        const int n = mk >> 6, sub = mk & 63;
        const float phv = ph_ws[brow_s * 64 + n];
        const float* src = (sub < 32)
            ? (xm_ws + brow_s * 2048 + n * Dd + sub)
            : (dl_ws + brow_s * 2048 + n * Dd + (sub - 32));
        v0 = *(const float4*)(src);
        v1 = *(const float4*)(src + 4);
        v0.x *= phv; v0.y *= phv; v0.z *= phv; v0.w *= phv;
        v1.x *= phv; v1.y *= phv; v1.z *= phv; v1.w *= phv;
      } else {
        const float* src = Vb + brow_s * 4096 + mk;
        v0 = *(const float4*)(src);
        v1 = *(const float4*)(src + 4);
      }
      const int k8 = agk * 8;
      At[k8 + 0][arow] = v0.x; At[k8 + 1][arow] = v0.y;
      At[k8 + 2][arow] = v0.z; At[k8 + 3][arow] = v0.w;
      At[k8 + 4][arow] = v1.x; At[k8 + 5][arow] = v1.y;
      At[k8 + 6][arow] = v1.z; At[k8 + 7][arow] = v1.w;
    }
    __syncthreads();
    // ---- compute ----
    #pragma unroll 8
    for (int kk = 0; kk < 64; kk++) {
      const float a0 = At[kk][ty * 2];
      const float a1 = At[kk][ty * 2 + 1];
      float4 wlo = *(const float4*)&Wt[kk][tx * 4];
      float4 whi = *(const float4*)&Wt[kk][(tx + 16) * 4];
      acc[0][0] += a0 * wlo.x; acc[0][1] += a0 * wlo.y;
      acc[0][2] += a0 * wlo.z; acc[0][3] += a0 * wlo.w;
      acc[0][4] += a0 * whi.x; acc[0][5] += a0 * whi.y;
      acc[0][6] += a0 * whi.z; acc[0][7] += a0 * whi.w;
      acc[1][0] += a1 * wlo.x; acc[1][1] += a1 * wlo.y;
      acc[1][2] += a1 * wlo.z; acc[1][3] += a1 * wlo.w;
      acc[1][4] += a1 * whi.x; acc[1][5] += a1 * whi.y;
      acc[1][6] += a1 * whi.z; acc[1][7] += a1 * whi.w;
    }
  }

  // ---- write partials ----
  #pragma unroll
  for (int r = 0; r < 2; r++) {
    const int brow = bg * 32 + ty * 2 + r;
    float* pr = part + (s * 256 + brow) * Cc;
    #pragma unroll
    for (int q = 0; q < 2; q++) {
      const int c0 = (tx + q * 16) * 4;
      if (c0 < Cc) {
        pr[c0 + 0] = acc[r][q * 4 + 0];
        pr[c0 + 1] = acc[r][q * 4 + 1];
        pr[c0 + 2] = acc[r][q * 4 + 2];
        pr[c0 + 3] = acc[r][q * 4 + 3];
      }
    }
  }
}

// ---------------------------------------------------------------------------
// Kernel C2: reduce partials + biases -> y.  grid 100 x 256 threads.
// ---------------------------------------------------------------------------
__global__ __launch_bounds__(256) void kC2(
    const float* __restrict__ part,    // [32][25600]
    const float* __restrict__ b1,
    const float* __restrict__ b2,
    float* __restrict__ out_y)         // [256][100] flat = 25600
{
  const int o = blockIdx.x * 256 + threadIdx.x;   // 0..25599
  const int c = o % Cc;
  float sum = b1[c] + b2[c];
  #pragma unroll
  for (int s = 0; s < 32; s++) sum += part[s * 25600 + o];
  out_y[o] = sum;
}

// ---------------------------------------------------------------------------
extern "C" void kernel_launch(void* const* d_in, const int* in_sizes, int n_in,
                              void* d_out, int out_size, void* d_ws, size_t ws_size,
                              hipStream_t stream) {
  const float* h  = (const float*)d_in[0];
  const float* Wc = (const float*)d_in[1];
  const float* bc = (const float*)d_in[2];
  const float* Wo = (const float*)d_in[3];
  const float* bo = (const float*)d_in[4];
  const float* Wp = (const float*)d_in[5];
  const float* bp = (const float*)d_in[6];
  const float* W1 = (const float*)d_in[7];
  const float* b1 = (const float*)d_in[8];
  const float* W2 = (const float*)d_in[9];
  const float* b2 = (const float*)d_in[10];

  float* out    = (float*)d_out;
  float* out_y  = out;                         // [256][100]
  float* out_ph = out + Bb * Cc;               // [256][64]
  float* out_V  = out + Bb * Cc + Bb * Nn;     // [256][64][64]

  float* xm   = (float*)d_ws;              // 524288 f32 (2 MB)
  float* dl   = xm + Bb * Nn * Dd;         // 524288 f32 (2 MB)
  float* ph   = dl + Bb * Nn * Dd;         // 16384 f32
  float* part = ph + Bb * Nn;              // 32*25600 f32 (3.28 MB)

  kA<<<dim3(Nn, Bb / 64), 256, 0, stream>>>(h, Wc, bc, Wo, bo, Wp, bp,
                                            xm, dl, ph, out_ph);
  kB<<<Bb, 256, 0, stream>>>(xm, dl, out_V);
  kC1<<<dim3(8, 32), 256, 0, stream>>>(xm, dl, ph, (const float*)out_V,
                                       W1, W2, part);
  kC2<<<100, 256, 0, stream>>>(part, b1, b2, out_y);
}

// Round 4
// 66.719 us; speedup vs baseline: 1.6694x; 1.1086x over previous
//
#include <hip/hip_runtime.h>
#include <hip/hip_bf16.h>
#include <cstdint>

// Problem constants (ConceptBoxModel): B=256, L=512, N=64, D=32, C=100
constexpr int Bb = 256, Ll = 512, Nn = 64, Dd = 32, Cc = 100;
constexpr float EPS = 1e-6f;

// ---------------------------------------------------------------------------
// Kernel A v2: x_m = h@Wc + bc ; delta = softplus(h@Wo + bo) ; p_hat
// grid (n=64, bt=4) = 256 blocks, 512 threads (8 waves).
// Intra-block split-K: waves 0-3 do K 0..255, waves 4-7 do K 256..511.
// Thread tile: 4 rows x (2 d-cols x 2 mats) = 16 FMA/kk vs ~24 LDS-cyc.
// ---------------------------------------------------------------------------
__global__ __launch_bounds__(512) void kA(
    const float* __restrict__ h,    // [256][512]
    const float* __restrict__ Wc,   // [64][512][32]
    const float* __restrict__ bc,   // [64][32]
    const float* __restrict__ Wo,
    const float* __restrict__ bo,
    const float* __restrict__ Wp,   // [64][64]
    const float* __restrict__ bp,   // [64]
    float* __restrict__ xm_ws,      // [256][64][32]
    float* __restrict__ dl_ws,      // [256][64][32]
    float* __restrict__ ph_ws,      // [256][64]
    float* __restrict__ out_ph)     // [256][64]
{
  const int n  = blockIdx.x;
  const int bt = blockIdx.y * 64;
  const int t  = threadIdx.x;     // 0..511
  const int kg = t >> 8;          // K-group 0/1
  const int tl = t & 255;         // id within group
  const int d0 = (tl & 15) * 2;   // cols d0, d0+1
  const int ty = tl >> 4;         // 0..15 -> rows ty*4 .. ty*4+3

  __shared__ union USm {
    struct {
      float hsT[2][32][68];       // [kg][kk][row], 272B rows (16B aligned)
      float wcs[2][32][32];       // [kg][kk][d]
      float wos[2][32][32];
    } s;
    float red[16][264];           // reduce buffer (16.9KB <= staging)
  } u;

  float accc[4][2] = {};
  float acco[4][2] = {};

  const int sr = tl >> 2, sk8 = (tl & 3) * 8;   // h staging map
  const float* wcb = Wc + n * (Ll * Dd);
  const float* wob = Wo + n * (Ll * Dd);

  for (int t8 = 0; t8 < 8; t8++) {
    const int k0 = kg * 256 + t8 * 32;
    __syncthreads();
    // stage h tile transposed: hsT[kg][kk][row]
    {
      const float* hp = h + (bt + sr) * Ll + k0 + sk8;
      float4 h0 = *(const float4*)(hp);
      float4 h1 = *(const float4*)(hp + 4);
      u.s.hsT[kg][sk8 + 0][sr] = h0.x; u.s.hsT[kg][sk8 + 1][sr] = h0.y;
      u.s.hsT[kg][sk8 + 2][sr] = h0.z; u.s.hsT[kg][sk8 + 3][sr] = h0.w;
      u.s.hsT[kg][sk8 + 4][sr] = h1.x; u.s.hsT[kg][sk8 + 5][sr] = h1.y;
      u.s.hsT[kg][sk8 + 6][sr] = h1.z; u.s.hsT[kg][sk8 + 7][sr] = h1.w;
    }
    // stage W tiles (32x32 contiguous)
    {
      float4 wv = *(const float4*)(wcb + k0 * Dd + tl * 4);
      float4 ov = *(const float4*)(wob + k0 * Dd + tl * 4);
      *(float4*)(&u.s.wcs[kg][0][0] + tl * 4) = wv;
      *(float4*)(&u.s.wos[kg][0][0] + tl * 4) = ov;
    }
    __syncthreads();
    #pragma unroll
    for (int kk = 0; kk < 32; kk++) {
      float4 hv  = *(const float4*)&u.s.hsT[kg][kk][ty * 4];
      float2 wcv = *(const float2*)&u.s.wcs[kg][kk][d0];
      float2 wov = *(const float2*)&u.s.wos[kg][kk][d0];
      accc[0][0] += hv.x * wcv.x; accc[0][1] += hv.x * wcv.y;
      accc[1][0] += hv.y * wcv.x; accc[1][1] += hv.y * wcv.y;
      accc[2][0] += hv.z * wcv.x; accc[2][1] += hv.z * wcv.y;
      accc[3][0] += hv.w * wcv.x; accc[3][1] += hv.w * wcv.y;
      acco[0][0] += hv.x * wov.x; acco[0][1] += hv.x * wov.y;
      acco[1][0] += hv.y * wov.x; acco[1][1] += hv.y * wov.y;
      acco[2][0] += hv.z * wov.x; acco[2][1] += hv.z * wov.y;
      acco[3][0] += hv.w * wov.x; acco[3][1] += hv.w * wov.y;
    }
  }

  // cross-group reduction (group 1 -> LDS -> group 0)
  __syncthreads();
  if (kg == 1) {
    #pragma unroll
    for (int r = 0; r < 4; r++) {
      u.red[r * 2 + 0][tl] = accc[r][0];
      u.red[r * 2 + 1][tl] = accc[r][1];
      u.red[8 + r * 2 + 0][tl] = acco[r][0];
      u.red[8 + r * 2 + 1][tl] = acco[r][1];
    }
  }
  __syncthreads();
  if (kg == 0) {
    const float2 bcv  = *(const float2*)(bc + n * Dd + d0);
    const float2 bov  = *(const float2*)(bo + n * Dd + d0);
    const float2 wplo = *(const float2*)(Wp + n * 64 + d0);
    const float2 wphi = *(const float2*)(Wp + n * 64 + 32 + d0);
    const float bpv = bp[n];
    #pragma unroll
    for (int r = 0; r < 4; r++) {
      const int b = bt + ty * 4 + r;
      const float xm0  = accc[r][0] + u.red[r * 2 + 0][tl] + bcv.x;
      const float xm1  = accc[r][1] + u.red[r * 2 + 1][tl] + bcv.y;
      const float pre0 = acco[r][0] + u.red[8 + r * 2 + 0][tl] + bov.x;
      const float pre1 = acco[r][1] + u.red[8 + r * 2 + 1][tl] + bov.y;
      // stable softplus
      const float dl0 = fmaxf(pre0, 0.f) + log1pf(expf(-fabsf(pre0)));
      const float dl1 = fmaxf(pre1, 0.f) + log1pf(expf(-fabsf(pre1)));
      *(float2*)(xm_ws + b * 2048 + n * Dd + d0) = make_float2(xm0, xm1);
      *(float2*)(dl_ws + b * 2048 + n * Dd + d0) = make_float2(dl0, dl1);
      float pp = xm0 * wplo.x + xm1 * wplo.y + dl0 * wphi.x + dl1 * wphi.y;
      pp += __shfl_xor(pp, 1);
      pp += __shfl_xor(pp, 2);
      pp += __shfl_xor(pp, 4);
      pp += __shfl_xor(pp, 8);
      if ((tl & 15) == 0) {
        const float ph = 1.f / (1.f + expf(-(pp + bpv)));
        ph_ws[b * 64 + n] = ph;
        out_ph[b * 64 + n] = ph;
      }
    }
  }
}

// ---------------------------------------------------------------------------
// Kernel B: pairwise intersection volumes V[b,i,j].  One block per b.
// ---------------------------------------------------------------------------
__global__ __launch_bounds__(256) void kB(
    const float* __restrict__ xm_ws,
    const float* __restrict__ dl_ws,
    float* __restrict__ out_V)      // [256][64][64]
{
  const int b = blockIdx.x, t = threadIdx.x;
  __shared__ float lo[64][36];   // pad 36: float4-aligned, banks spread
  __shared__ float hi[64][36];
  __shared__ float rvol[64];

  {
    const int n = t >> 2, dd = (t & 3) * 8;
    const float* xp = xm_ws + b * 2048 + n * Dd + dd;
    const float* dp = dl_ws + b * 2048 + n * Dd + dd;
    #pragma unroll
    for (int i = 0; i < 8; i += 4) {
      float4 x = *(const float4*)(xp + i);
      float4 g = *(const float4*)(dp + i);
      lo[n][dd + i + 0] = x.x - g.x;  hi[n][dd + i + 0] = x.x + g.x;
      lo[n][dd + i + 1] = x.y - g.y;  hi[n][dd + i + 1] = x.y + g.y;
      lo[n][dd + i + 2] = x.z - g.z;  hi[n][dd + i + 2] = x.z + g.z;
      lo[n][dd + i + 3] = x.w - g.w;  hi[n][dd + i + 3] = x.w + g.w;
    }
  }
  if (t < 64) {
    const float* dp = dl_ws + b * 2048 + t * Dd;
    float p = 1.f;
    #pragma unroll
    for (int dd = 0; dd < 32; dd++) p *= dp[dd] + EPS;
    rvol[t] = 1.f / p;
  }
  __syncthreads();

  const int i0 = t >> 6;    // wave id -> i uniform per wave
  const int j  = t & 63;
  #pragma unroll 1
  for (int it = 0; it < 16; it++) {
    const int i = i0 + 4 * it;
    float prod = 1.f;
    #pragma unroll
    for (int dd = 0; dd < 32; dd += 4) {
      float4 hj = *(const float4*)&hi[j][dd];
      float4 lj = *(const float4*)&lo[j][dd];
      float4 hv = *(const float4*)&hi[i][dd];   // broadcast
      float4 lv = *(const float4*)&lo[i][dd];   // broadcast
      float v0 = fmaxf(fminf(hv.x, hj.x) - fmaxf(lv.x, lj.x), 0.f) * 0.5f + EPS;
      float v1 = fmaxf(fminf(hv.y, hj.y) - fmaxf(lv.y, lj.y), 0.f) * 0.5f + EPS;
      float v2 = fmaxf(fminf(hv.z, hj.z) - fmaxf(lv.z, lj.z), 0.f) * 0.5f + EPS;
      float v3 = fmaxf(fminf(hv.w, hj.w) - fmaxf(lv.w, lj.w), 0.f) * 0.5f + EPS;
      prod *= v0 * v1 * v2 * v3;
    }
    out_V[b * 4096 + i * 64 + j] = prod * rvol[j];
  }
}

// ---------------------------------------------------------------------------
// Kernel C1: split-K GEMM partials.
//   A = concat([aligned, V]) : [256][8192], W = [W1; W2] : [8192][100]
// ---------------------------------------------------------------------------
__global__ __launch_bounds__(256) void kC1(
    const float* __restrict__ xm_ws,   // [256][2048]
    const float* __restrict__ dl_ws,   // [256][2048]
    const float* __restrict__ ph_ws,   // [256][64]
    const float* __restrict__ Vb,      // [256][4096] (from d_out)
    const float* __restrict__ W1,      // [4096][100]
    const float* __restrict__ W2,      // [4096][100]
    float* __restrict__ part)          // [32][256][100]
{
  const int bg = blockIdx.x;           // 8 row-groups of 32
  const int s  = blockIdx.y;           // 32 K-slices
  const bool isV = (s >= 16);
  const int m0 = (s & 15) * 256;       // type-local K offset, KSL=256
  const float* __restrict__ W = isV ? W2 : W1;

  __shared__ float Wt[64][132];        // [kk][col]
  __shared__ float At[64][33];         // [kk][row]

  const int t  = threadIdx.x;
  const int tx = t & 15;               // col quads tx, tx+16
  const int ty = t >> 4;               // rows ty*2, ty*2+1

  float acc[2][8] = {};

  const int wrw = t >> 2, wq8 = (t & 3) * 8;       // W: row, granule base
  const int arow = t >> 3, agk = t & 7;            // A: row, kk-octet
  const int brow_s = bg * 32 + arow;

  for (int ch = 0; ch < 4; ch++) {
    const int mbase = m0 + ch * 64;
    __syncthreads();
    // ---- stage W chunk ----
    {
      const float* wr = W + (mbase + wrw) * Cc;
      #pragma unroll
      for (int j = 0; j < 8; j++) {
        const int c = (wq8 + j) * 4;
        float4 v = make_float4(0.f, 0.f, 0.f, 0.f);
        if (c < Cc) v = *(const float4*)(wr + c);
        *(float4*)&Wt[wrw][c] = v;
      }
    }
    // ---- stage A chunk [64 kk][32 rows] ----
    {
      const int mk = mbase + agk * 8;
      float4 v0, v1;
      if (!isV) {
        const int n = mk >> 6, sub = mk & 63;
        const float phv = ph_ws[brow_s * 64 + n];
        const float* src = (sub < 32)
            ? (xm_ws + brow_s * 2048 + n * Dd + sub)
            : (dl_ws + brow_s * 2048 + n * Dd + (sub - 32));
        v0 = *(const float4*)(src);
        v1 = *(const float4*)(src + 4);
        v0.x *= phv; v0.y *= phv; v0.z *= phv; v0.w *= phv;
        v1.x *= phv; v1.y *= phv; v1.z *= phv; v1.w *= phv;
      } else {
        const float* src = Vb + brow_s * 4096 + mk;
        v0 = *(const float4*)(src);
        v1 = *(const float4*)(src + 4);
      }
      const int k8 = agk * 8;
      At[k8 + 0][arow] = v0.x; At[k8 + 1][arow] = v0.y;
      At[k8 + 2][arow] = v0.z; At[k8 + 3][arow] = v0.w;
      At[k8 + 4][arow] = v1.x; At[k8 + 5][arow] = v1.y;
      At[k8 + 6][arow] = v1.z; At[k8 + 7][arow] = v1.w;
    }
    __syncthreads();
    // ---- compute ----
    #pragma unroll 8
    for (int kk = 0; kk < 64; kk++) {
      const float a0 = At[kk][ty * 2];
      const float a1 = At[kk][ty * 2 + 1];
      float4 wlo = *(const float4*)&Wt[kk][tx * 4];
      float4 whi = *(const float4*)&Wt[kk][(tx + 16) * 4];
      acc[0][0] += a0 * wlo.x; acc[0][1] += a0 * wlo.y;
      acc[0][2] += a0 * wlo.z; acc[0][3] += a0 * wlo.w;
      acc[0][4] += a0 * whi.x; acc[0][5] += a0 * whi.y;
      acc[0][6] += a0 * whi.z; acc[0][7] += a0 * whi.w;
      acc[1][0] += a1 * wlo.x; acc[1][1] += a1 * wlo.y;
      acc[1][2] += a1 * wlo.z; acc[1][3] += a1 * wlo.w;
      acc[1][4] += a1 * whi.x; acc[1][5] += a1 * whi.y;
      acc[1][6] += a1 * whi.z; acc[1][7] += a1 * whi.w;
    }
  }

  #pragma unroll
  for (int r = 0; r < 2; r++) {
    const int brow = bg * 32 + ty * 2 + r;
    float* pr = part + (s * 256 + brow) * Cc;
    #pragma unroll
    for (int q = 0; q < 2; q++) {
      const int c0 = (tx + q * 16) * 4;
      if (c0 < Cc) {
        pr[c0 + 0] = acc[r][q * 4 + 0];
        pr[c0 + 1] = acc[r][q * 4 + 1];
        pr[c0 + 2] = acc[r][q * 4 + 2];
        pr[c0 + 3] = acc[r][q * 4 + 3];
      }
    }
  }
}

// ---------------------------------------------------------------------------
// Kernel C2: reduce partials + biases -> y.  grid 100 x 256 threads.
// ---------------------------------------------------------------------------
__global__ __launch_bounds__(256) void kC2(
    const float* __restrict__ part,    // [32][25600]
    const float* __restrict__ b1,
    const float* __restrict__ b2,
    float* __restrict__ out_y)         // [256][100] flat = 25600
{
  const int o = blockIdx.x * 256 + threadIdx.x;   // 0..25599
  const int c = o % Cc;
  float sum = b1[c] + b2[c];
  #pragma unroll
  for (int s = 0; s < 32; s++) sum += part[s * 25600 + o];
  out_y[o] = sum;
}

// ---------------------------------------------------------------------------
extern "C" void kernel_launch(void* const* d_in, const int* in_sizes, int n_in,
                              void* d_out, int out_size, void* d_ws, size_t ws_size,
                              hipStream_t stream) {
  const float* h  = (const float*)d_in[0];
  const float* Wc = (const float*)d_in[1];
  const float* bc = (const float*)d_in[2];
  const float* Wo = (const float*)d_in[3];
  const float* bo = (const float*)d_in[4];
  const float* Wp = (const float*)d_in[5];
  const float* bp = (const float*)d_in[6];
  const float* W1 = (const float*)d_in[7];
  const float* b1 = (const float*)d_in[8];
  const float* W2 = (const float*)d_in[9];
  const float* b2 = (const float*)d_in[10];

  float* out    = (float*)d_out;
  float* out_y  = out;                         // [256][100]
  float* out_ph = out + Bb * Cc;               // [256][64]
  float* out_V  = out + Bb * Cc + Bb * Nn;     // [256][64][64]

  float* xm   = (float*)d_ws;              // 524288 f32 (2 MB)
  float* dl   = xm + Bb * Nn * Dd;         // 524288 f32 (2 MB)
  float* ph   = dl + Bb * Nn * Dd;         // 16384 f32
  float* part = ph + Bb * Nn;              // 32*25600 f32 (3.28 MB)

  kA<<<dim3(Nn, Bb / 64), 512, 0, stream>>>(h, Wc, bc, Wo, bo, Wp, bp,
                                            xm, dl, ph, out_ph);
  kB<<<Bb, 256, 0, stream>>>(xm, dl, out_V);
  kC1<<<dim3(8, 32), 256, 0, stream>>>(xm, dl, ph, (const float*)out_V,
                                       W1, W2, part);
  kC2<<<100, 256, 0, stream>>>(part, b1, b2, out_y);
}